// Round 6
// baseline (802.456 us; speedup 1.0000x reference)
//
#include <hip/hip_runtime.h>
#include <hip/hip_bf16.h>

using bf16   = __bf16;
using bf16x4 = __attribute__((ext_vector_type(4))) __bf16;
using bf16x8 = __attribute__((ext_vector_type(8))) __bf16;
using f32x4  = __attribute__((ext_vector_type(4))) float;

#define B_TOT 2048
#define NTOK  98
#define CDIM  192
#define NHEAD 6
#define HDIM  32
#define NWIN  512
#define NN    (NTOK*NTOK)            /* 9604 */
#define SCALE 0.17677669529663687f   /* 32^-0.5 */

#define MFMA(a,b,c) __builtin_amdgcn_mfma_f32_16x16x32_bf16((a),(b),(c),0,0,0)

// ---------------------------------------------------------------------------
// bias[h][i][j] = rpb_table[rel_pos_index[i*98+j]][h]
// ---------------------------------------------------------------------------
__global__ void build_bias(const float* __restrict__ table,
                           const int* __restrict__ rel,
                           float* __restrict__ bias) {
    int t = blockIdx.x * 256 + threadIdx.x;
    if (t < NN) {
        int idx = rel[t];
        #pragma unroll
        for (int h = 0; h < NHEAD; ++h)
            bias[h * NN + t] = table[idx * NHEAD + h];
    }
}

// f32 -> bf16 weight conversion
__global__ void wconv(const float* __restrict__ w, bf16* __restrict__ wb, int n) {
    int t = blockIdx.x * 256 + threadIdx.x;
    if (t < n) wb[t] = (bf16)w[t];
}

// ---------------------------------------------------------------------------
// Fused QKV + attention: one block per WINDOW (2048 blocks, 7 waves).
// Each wave keeps its 16 x-rows as bf16 MFMA fragments in registers (x read
// from HBM exactly once). Per head: in-block GEMMs produce Q (scaled+bias),
// K, V^T into LDS; then QK^T -> softmax (deferred norm) -> PV as before.
// Eliminates the 231MB q/k/v intermediate write + re-read entirely.
// ---------------------------------------------------------------------------
__global__ __launch_bounds__(448, 4) void win_attn(
    const float* __restrict__ x, const bf16* __restrict__ wb,
    const float* __restrict__ bvec,
    const float* __restrict__ mask, const float* __restrict__ bias,
    bf16* __restrict__ ao)
{
    __shared__ char lds[7168 + 7168 + 8192 + 28672 + 512];
    char* Qs = lds;                     // 112 x 64B rows, chunk ^= row&3 swizzle
    char* Ks = lds + 7168;              // 112 x 64B rows
    char* Vt = lds + 14336;             // 32 x 256B rows (col n swizzled)
    char* P  = lds + 22528;             // 112 x 256B rows
    float* invS = (float*)(lds + 51200);

    const int b = blockIdx.x;
    const int w = b & (NWIN - 1);
    const int tid = threadIdx.x, lane = tid & 63, wv = tid >> 6;  // wave 0..6
    const int l15 = lane & 15, l16 = lane >> 4;

    // ---- x fragments in registers (wave-private rows, f32 -> bf16) ----
    int nrow = wv * 16 + l15; if (nrow > 97) nrow = 97;
    const float* xr = x + ((size_t)b * NTOK + nrow) * CDIM + l16 * 8;
    bf16x8 xf[6];
    #pragma unroll
    for (int ks = 0; ks < 6; ++ks) {
        float4 v0 = *(const float4*)(xr + ks * 32);
        float4 v1 = *(const float4*)(xr + ks * 32 + 4);
        bf16x8 a;
        a[0] = (bf16)v0.x; a[1] = (bf16)v0.y; a[2] = (bf16)v0.z; a[3] = (bf16)v0.w;
        a[4] = (bf16)v1.x; a[5] = (bf16)v1.y; a[6] = (bf16)v1.z; a[7] = (bf16)v1.w;
        xf[ks] = a;
    }

    // ---- mask into registers (reused by all 6 heads) ----
    const float* mrow = mask + (size_t)w * NN;
    int irow[4];
    float mreg[7][4];
    #pragma unroll
    for (int r = 0; r < 4; ++r) {
        int i = wv * 16 + l16 * 4 + r; if (i > 97) i = 97;
        irow[r] = i;
        #pragma unroll
        for (int jt = 0; jt < 7; ++jt) {
            int j = jt * 16 + l15;
            mreg[jt][r] = (j < NTOK) ? mrow[i * NTOK + j] : 0.f;
        }
    }

    // ---- one-time pad zeroing: Vt cols 112..127, P cols 112..127 ----
    for (int f = tid; f < 32 * 30; f += 448) {
        int hd = f / 30, n = 98 + f % 30;
        *(bf16*)(Vt + hd * 256 + (((n >> 3) ^ (hd & 7)) << 4) + ((n & 7) << 1)) = (bf16)0.f;
    }
    {
        int zr = wv * 16 + l15;
        int zc = 112 + l16 * 4;
        *(unsigned long long*)(P + zr * 256 + (((zc >> 3) ^ (zr & 7)) << 4) + ((zc & 7) << 1)) = 0ull;
    }

    const f32x4 z4 = {0.f, 0.f, 0.f, 0.f};

    for (int h = 0; h < NHEAD; ++h) {
        // ======== in-block QKV GEMMs for this head ========
        // Q: D lane holds Q[wv*16 + l16*4+r][t*16 + l15]
        #pragma unroll
        for (int t = 0; t < 2; ++t) {
            f32x4 a = z4;
            const bf16* wq = wb + (size_t)(h * 32 + t * 16 + l15) * CDIM + l16 * 8;
            #pragma unroll
            for (int ks = 0; ks < 6; ++ks)
                a = MFMA(xf[ks], *(const bf16x8*)(wq + ks * 32), a);
            const float bq = bvec[h * 32 + t * 16 + l15];
            #pragma unroll
            for (int r = 0; r < 4; ++r) {
                int row = wv * 16 + l16 * 4 + r;
                float v = (a[r] + bq) * SCALE;
                *(bf16*)(Qs + row * 64 + (((t * 2 + (l15 >> 3)) ^ (row & 3)) << 4)
                         + ((l15 & 7) << 1)) = (bf16)v;
            }
        }
        // K
        #pragma unroll
        for (int t = 0; t < 2; ++t) {
            f32x4 a = z4;
            const bf16* wk = wb + (size_t)(CDIM + h * 32 + t * 16 + l15) * CDIM + l16 * 8;
            #pragma unroll
            for (int ks = 0; ks < 6; ++ks)
                a = MFMA(xf[ks], *(const bf16x8*)(wk + ks * 32), a);
            const float bk = bvec[CDIM + h * 32 + t * 16 + l15];
            #pragma unroll
            for (int r = 0; r < 4; ++r) {
                int row = wv * 16 + l16 * 4 + r;
                float v = a[r] + bk;
                *(bf16*)(Ks + row * 64 + (((t * 2 + (l15 >> 3)) ^ (row & 3)) << 4)
                         + ((l15 & 7) << 1)) = (bf16)v;
            }
        }
        // V^T: swapped operands; D lane holds Vt[t*16 + l16*4+r][wv*16 + l15]
        #pragma unroll
        for (int t = 0; t < 2; ++t) {
            f32x4 a = z4;
            const bf16* wvp = wb + (size_t)(2 * CDIM + h * 32 + t * 16 + l15) * CDIM + l16 * 8;
            #pragma unroll
            for (int ks = 0; ks < 6; ++ks)
                a = MFMA(*(const bf16x8*)(wvp + ks * 32), xf[ks], a);
            const float4 bv4 = *(const float4*)(bvec + 2 * CDIM + h * 32 + t * 16 + l16 * 4);
            #pragma unroll
            for (int r = 0; r < 4; ++r) {
                int hd = t * 16 + l16 * 4 + r;
                int n  = wv * 16 + l15;
                float v = a[r] + ((const float*)&bv4)[r];
                *(bf16*)(Vt + hd * 256 + (((n >> 3) ^ (hd & 7)) << 4) + ((n & 7) << 1)) = (bf16)v;
            }
        }
        __syncthreads();   // barrier A: Q/K/Vt visible to all waves

        // ======== attention ========
        const int qr = wv * 16 + l15;
        const bf16x8 qf = *(const bf16x8*)(Qs + qr * 64 + ((l16 ^ (qr & 3)) << 4));
        f32x4 acc[7];
        #pragma unroll
        for (int jt = 0; jt < 7; ++jt) {
            int kr = jt * 16 + l15;
            bf16x8 kf = *(const bf16x8*)(Ks + kr * 64 + ((l16 ^ (kr & 3)) << 4));
            acc[jt] = MFMA(qf, kf, z4);
        }

        const float* brow = bias + (size_t)h * NN;
        #pragma unroll
        for (int r = 0; r < 4; ++r) {
            const int iact = wv * 16 + l16 * 4 + r;
            #pragma unroll
            for (int jt = 0; jt < 7; ++jt) {
                int j = jt * 16 + l15;
                acc[jt][r] = (j < NTOK)
                    ? (acc[jt][r] + mreg[jt][r] + brow[irow[r] * NTOK + j])
                    : -__builtin_inff();
            }
            float m = acc[0][r];
            #pragma unroll
            for (int jt = 1; jt < 7; ++jt) m = fmaxf(m, acc[jt][r]);
            m = fmaxf(m, __shfl_xor(m, 1, 16));
            m = fmaxf(m, __shfl_xor(m, 2, 16));
            m = fmaxf(m, __shfl_xor(m, 4, 16));
            m = fmaxf(m, __shfl_xor(m, 8, 16));
            float s = 0.f;
            #pragma unroll
            for (int jt = 0; jt < 7; ++jt) {
                float e = __expf(acc[jt][r] - m);
                acc[jt][r] = e; s += e;
            }
            s += __shfl_xor(s, 1, 16);
            s += __shfl_xor(s, 2, 16);
            s += __shfl_xor(s, 4, 16);
            s += __shfl_xor(s, 8, 16);
            if (l15 == 0) invS[iact] = 1.f / s;
        }

        // unnormalized P (own wave's rows only — within-wave use)
        #pragma unroll
        for (int jt = 0; jt < 7; ++jt) {
            #pragma unroll
            for (int r = 0; r < 4; ++r) {
                int row = wv * 16 + l16 * 4 + r;
                int j = jt * 16 + l15;
                *(bf16*)(P + row * 256 + (((j >> 3) ^ (row & 7)) << 4) + ((j & 7) << 1))
                    = (bf16)acc[jt][r];
            }
        }

        // PV (operand-swapped): lane holds row = wv*16+l15, cols hd = l16*4+r (+16)
        f32x4 o0 = z4, o1 = z4;
        const int prow = wv * 16 + l15;
        #pragma unroll
        for (int ks = 0; ks < 4; ++ks) {
            int kchunk = ks * 4 + l16;
            bf16x8 pf = *(const bf16x8*)(P + prow * 256 + ((kchunk ^ (prow & 7)) << 4));
            bf16x8 v0 = *(const bf16x8*)(Vt + l15 * 256 + ((kchunk ^ (l15 & 7)) << 4));
            bf16x8 v1 = *(const bf16x8*)(Vt + (16 + l15) * 256 + ((kchunk ^ (l15 & 7)) << 4));
            o0 = MFMA(v0, pf, o0);
            o1 = MFMA(v1, pf, o1);
        }

        {
            int row = wv * 16 + l15;
            if (row < NTOK) {
                float inv = invS[row];
                bf16* dst = ao + (size_t)b * NTOK * CDIM + h * HDIM;
                bf16x4 s0, s1;
                #pragma unroll
                for (int r = 0; r < 4; ++r) {
                    s0[r] = (bf16)(o0[r] * inv);
                    s1[r] = (bf16)(o1[r] * inv);
                }
                *(bf16x4*)(dst + (size_t)row * CDIM + l16 * 4)      = s0;
                *(bf16x4*)(dst + (size_t)row * CDIM + 16 + l16 * 4) = s1;
            }
        }
        __syncthreads();   // barrier B: all reads of Qs/Ks/Vt done before next head
    }
}

// ---------------------------------------------------------------------------
// Proj GEMM v5 (unchanged): one wave per block, no LDS, depth-2 B prefetch.
// ---------------------------------------------------------------------------
__global__ __launch_bounds__(64, 2) void proj_gemm(
    const bf16* __restrict__ ao, const bf16* __restrict__ wb,
    const float* __restrict__ bvec, float* __restrict__ out)
{
    const int lane = threadIdx.x;
    const int l15 = lane & 15, l16 = lane >> 4;
    const int m0  = blockIdx.x * 64;

    bf16x8 af[4][6];
    #pragma unroll
    for (int it = 0; it < 4; ++it) {
        const bf16* ar = ao + (size_t)(m0 + it * 16 + l15) * CDIM + l16 * 8;
        #pragma unroll
        for (int ks = 0; ks < 6; ++ks)
            af[it][ks] = *(const bf16x8*)(ar + ks * 32);
    }

    int rowoff[4];
    #pragma unroll
    for (int it = 0; it < 4; ++it)
        rowoff[it] = (m0 + it * 16 + l15) * CDIM;

    const bf16* wlane = wb + (size_t)l15 * CDIM + l16 * 8;

    const f32x4 z4 = {0.f, 0.f, 0.f, 0.f};
    f32x4 acc[4][4];
    bf16x8 bbuf[3][4];

    #pragma unroll
    for (int ct = 0; ct < 4; ++ct) {
        bbuf[0][ct] = *(const bf16x8*)(wlane + (size_t)(ct * 16) * CDIM);
        bbuf[1][ct] = *(const bf16x8*)(wlane + (size_t)(ct * 16) * CDIM + 32);
    }

    #pragma unroll
    for (int t = 0; t < 18; ++t) {
        const int nc = t / 6, ks = t % 6;
        if (ks == 0) {
            #pragma unroll
            for (int it = 0; it < 4; ++it)
                #pragma unroll
                for (int ct = 0; ct < 4; ++ct) acc[it][ct] = z4;
        }
        if (t < 16) {
            const int tn = t + 2, nn = tn / 6, kk = tn % 6;
            #pragma unroll
            for (int ct = 0; ct < 4; ++ct)
                bbuf[tn % 3][ct] =
                    *(const bf16x8*)(wlane + (size_t)(nn * 64 + ct * 16) * CDIM + kk * 32);
        }
        #pragma unroll
        for (int ct = 0; ct < 4; ++ct) {
            #pragma unroll
            for (int it = 0; it < 4; ++it)
                acc[it][ct] = MFMA(bbuf[t % 3][ct], af[it][ks], acc[it][ct]);
        }
        if (ks == 5) {
            #pragma unroll
            for (int ct = 0; ct < 4; ++ct) {
                const int g0 = nc * 64 + ct * 16;
                const float4 bvf = *(const float4*)(bvec + g0 + l16 * 4);
                #pragma unroll
                for (int it = 0; it < 4; ++it) {
                    f32x4 s;
                    #pragma unroll
                    for (int r = 0; r < 4; ++r)
                        s[r] = acc[it][ct][r] + ((const float*)&bvf)[r];
                    *(f32x4*)(out + (size_t)rowoff[it] + g0 + l16 * 4) = s;
                }
            }
        }
    }
}

// ---------------------------------------------------------------------------
extern "C" void kernel_launch(void* const* d_in, const int* in_sizes, int n_in,
                              void* d_out, int out_size, void* d_ws, size_t ws_size,
                              hipStream_t stream)
{
    (void)in_sizes; (void)n_in; (void)out_size; (void)ws_size;
    const float* x      = (const float*)d_in[0];
    const float* mask   = (const float*)d_in[1];
    const float* qkv_w  = (const float*)d_in[2];
    const float* qkv_b  = (const float*)d_in[3];
    const float* proj_w = (const float*)d_in[4];
    const float* proj_b = (const float*)d_in[5];
    const float* rpb    = (const float*)d_in[6];
    const int*   rel    = (const int*)d_in[7];
    float* out = (float*)d_out;

    char* ws = (char*)d_ws;
    float* bias = (float*)ws;                                 // 230,496 B
    size_t off = ((size_t)NHEAD * NN * 4 + 255) / 256 * 256;
    bf16* qwb = (bf16*)(ws + off);                            // 3*192*192 bf16
    off += (size_t)3 * CDIM * CDIM * sizeof(bf16);
    bf16* pwb = (bf16*)(ws + off);                            // 192*192 bf16
    off += (size_t)CDIM * CDIM * sizeof(bf16);
    off = (off + 255) / 256 * 256;
    bf16* ao  = (bf16*)(ws + off);                            // 77,070,336 B

    build_bias<<<(NN + 255) / 256, 256, 0, stream>>>(rpb, rel, bias);
    wconv<<<(3 * CDIM * CDIM + 255) / 256, 256, 0, stream>>>(qkv_w, qwb, 3 * CDIM * CDIM);
    wconv<<<(CDIM * CDIM + 255) / 256, 256, 0, stream>>>(proj_w, pwb, CDIM * CDIM);
    win_attn<<<B_TOT, 448, 0, stream>>>(x, qwb, qkv_b, mask, bias, ao);
    proj_gemm<<<200704 / 64, 64, 0, stream>>>(ao, pwb, proj_b, out);
}

// Round 7
// 675.940 us; speedup vs baseline: 1.1872x; 1.1872x over previous
//
#include <hip/hip_runtime.h>
#include <hip/hip_bf16.h>

using bf16   = __bf16;
using bf16x4 = __attribute__((ext_vector_type(4))) __bf16;
using bf16x8 = __attribute__((ext_vector_type(8))) __bf16;
using f32x4  = __attribute__((ext_vector_type(4))) float;

#define B_TOT 2048
#define NTOK  98
#define CDIM  192
#define NHEAD 6
#define HDIM  32
#define NWIN  512
#define NN    (NTOK*NTOK)            /* 9604 */
#define QKV_ELEMS ((size_t)B_TOT*NHEAD*NTOK*HDIM)  /* 38535168 */
#define SCALE 0.17677669529663687f   /* 32^-0.5 */

#define MFMA(a,b,c) __builtin_amdgcn_mfma_f32_16x16x32_bf16((a),(b),(c),0,0,0)

// ---------------------------------------------------------------------------
// bias[h][i][j] = rpb_table[rel_pos_index[i*98+j]][h]
// ---------------------------------------------------------------------------
__global__ void build_bias(const float* __restrict__ table,
                           const int* __restrict__ rel,
                           float* __restrict__ bias) {
    int t = blockIdx.x * 256 + threadIdx.x;
    if (t < NN) {
        int idx = rel[t];
        #pragma unroll
        for (int h = 0; h < NHEAD; ++h)
            bias[h * NN + t] = table[idx * NHEAD + h];
    }
}

// f32 -> bf16 weight conversion (into dead ws regions)
__global__ void wconv(const float* __restrict__ w, bf16* __restrict__ wb, int n) {
    int t = blockIdx.x * 256 + threadIdx.x;
    if (t < n) wb[t] = (bf16)w[t];
}

// ---------------------------------------------------------------------------
// QKV GEMM v6: MLP-oriented. 16 rows per WAVE, 4 waves per block (no LDS,
// no barriers) -> 12544 waves = 12.25/SIMD grid-average (vs 3.06 in v5).
// Depth-3 quad-buffered B prefetch -> ~12 outstanding 16B loads per wave.
// Aggregate outstanding bytes/SIMD ~2KB -> HBM can run near peak.
// VGPR budget: af 24 + acc 16 + bbuf 64 + misc ~ 125 (no spills).
// ---------------------------------------------------------------------------
__global__ __launch_bounds__(256) void qkv_gemm(
    const float* __restrict__ x, const bf16* __restrict__ wb,
    const float* __restrict__ bvec,
    bf16* __restrict__ qdst, bf16* __restrict__ kdst, bf16* __restrict__ vdst)
{
    const int tid = threadIdx.x, lane = tid & 63, wv = tid >> 6;
    const int l15 = lane & 15, l16 = lane >> 4;
    const int row = blockIdx.x * 64 + wv * 16 + l15;

    // A fragments: wave-private 16 rows, f32 -> bf16 in regs (x read once)
    bf16x8 af[6];
    {
        const float* xr = x + (size_t)row * CDIM + l16 * 8;
        #pragma unroll
        for (int ks = 0; ks < 6; ++ks) {
            float4 v0 = *(const float4*)(xr + ks * 32);
            float4 v1 = *(const float4*)(xr + ks * 32 + 4);
            bf16x8 a;
            a[0] = (bf16)v0.x; a[1] = (bf16)v0.y; a[2] = (bf16)v0.z; a[3] = (bf16)v0.w;
            a[4] = (bf16)v1.x; a[5] = (bf16)v1.y; a[6] = (bf16)v1.z; a[7] = (bf16)v1.w;
            af[ks] = a;
        }
    }

    const int rowoff = (row / NTOK) * 18816 + (row % NTOK) * 32;
    const bf16* wlane = wb + (size_t)l15 * CDIM + l16 * 8;

    const f32x4 z4 = {0.f, 0.f, 0.f, 0.f};
    f32x4 acc[4];
    bf16x8 bbuf[4][4];   // quad buffer, statically indexed after unroll

    // preload steps 0..2 (nc=0, ks=0..2)
    #pragma unroll
    for (int p = 0; p < 3; ++p) {
        #pragma unroll
        for (int ct = 0; ct < 4; ++ct)
            bbuf[p][ct] = *(const bf16x8*)(wlane + (size_t)(ct * 16) * CDIM + p * 32);
    }

    #pragma unroll
    for (int t = 0; t < 54; ++t) {
        const int nc = t / 6, ks = t % 6;
        if (ks == 0) {
            #pragma unroll
            for (int ct = 0; ct < 4; ++ct) acc[ct] = z4;
        }
        if (t < 51) {   // prefetch step t+3
            const int tn = t + 3, nn = tn / 6, kk = tn % 6;
            #pragma unroll
            for (int ct = 0; ct < 4; ++ct)
                bbuf[tn & 3][ct] =
                    *(const bf16x8*)(wlane + (size_t)(nn * 64 + ct * 16) * CDIM + kk * 32);
        }
        #pragma unroll
        for (int ct = 0; ct < 4; ++ct)
            acc[ct] = MFMA(bbuf[t & 3][ct], af[ks], acc[ct]);

        if (ks == 5) {   // epilogue for chunk nc: lane holds row=l15, cols l16*4+r
            #pragma unroll
            for (int ct = 0; ct < 4; ++ct) {
                const int g0    = nc * 64 + ct * 16;   // compile-time
                const int which = g0 / CDIM;
                const int cm    = g0 % CDIM;
                const int h     = cm >> 5, hd0 = cm & 31;
                const float4 bvf = *(const float4*)(bvec + g0 + l16 * 4);
                bf16x4 s;
                #pragma unroll
                for (int r = 0; r < 4; ++r) {
                    float v = acc[ct][r] + ((const float*)&bvf)[r];
                    if (which == 0) v *= SCALE;
                    s[r] = (bf16)v;
                }
                bf16* dp = (which == 0) ? qdst : (which == 1) ? kdst : vdst;
                *(bf16x4*)(dp + rowoff + h * 3136 + hd0 + l16 * 4) = s;
            }
        }
    }
}

// ---------------------------------------------------------------------------
// Fused attention (unchanged from round 5): one block per (window, head),
// 7 waves, one barrier, deferred softmax normalization, XCD-chunked swizzle.
// ---------------------------------------------------------------------------
__global__ __launch_bounds__(448) void attn_fused(
    const bf16* __restrict__ q, const bf16* __restrict__ k,
    const bf16* __restrict__ v,
    const float* __restrict__ mask, const float* __restrict__ bias,
    bf16* __restrict__ ao)
{
    __shared__ char lds[8192 + 28672 + 512];
    char* Vt = lds;           // 32 x 128 bf16, 256B rows, swizzled
    char* P  = lds + 8192;    // 112 x 128 bf16, 256B rows, swizzled
    float* invS = (float*)(lds + 8192 + 28672);   // 112 floats

    const int bid = blockIdx.x;
    const int bh  = (bid & 7) * 1536 + (bid >> 3);
    const int b = bh / NHEAD, h = bh % NHEAD;
    const int w = b & (NWIN - 1);
    const int tid = threadIdx.x, lane = tid & 63, it = tid >> 6;
    const int l15 = lane & 15, l16 = lane >> 4;

    const size_t bho = (size_t)bh * 3136;
    if (tid < 392) {
        int n = tid >> 2, hd0 = (tid & 3) * 8;
        bf16x8 vv = *(const bf16x8*)(v + bho + n * 32 + hd0);
        #pragma unroll
        for (int e = 0; e < 8; ++e) {
            int hd = hd0 + e;
            *(bf16*)(Vt + hd * 256 + (((n >> 3) ^ (hd & 7)) << 4) + ((n & 7) << 1)) = vv[e];
        }
    }
    for (int f = tid; f < 32 * 30; f += 448) {
        int hd = f / 30, n = 98 + f % 30;
        *(bf16*)(Vt + hd * 256 + (((n >> 3) ^ (hd & 7)) << 4) + ((n & 7) << 1)) = (bf16)0.f;
    }
    {
        int zr = it * 16 + l15;
        int zc = 112 + l16 * 4;
        *(unsigned long long*)(P + zr * 256 + (((zc >> 3) ^ (zr & 7)) << 4) + ((zc & 7) << 1)) = 0ull;
    }

    int qrow = it * 16 + l15; if (qrow > 97) qrow = 97;
    const bf16* qsrc = q + bho;
    const bf16* ksrc = k + bho;
    const bf16x8 qf = *(const bf16x8*)(qsrc + qrow * HDIM + l16 * 8);
    const f32x4 z4 = {0.f, 0.f, 0.f, 0.f};
    f32x4 acc[7];
    #pragma unroll
    for (int jt = 0; jt < 7; ++jt) {
        int kr = jt * 16 + l15; if (kr > 97) kr = 97;
        bf16x8 kf = *(const bf16x8*)(ksrc + kr * HDIM + l16 * 8);
        acc[jt] = MFMA(qf, kf, z4);
    }

    const float* mrow = mask + (size_t)w * NN;
    const float* brow = bias + (size_t)h * NN;
    #pragma unroll
    for (int r = 0; r < 4; ++r) {
        const int iact = it * 16 + l16 * 4 + r;
        int i = iact > 97 ? 97 : iact;
        #pragma unroll
        for (int jt = 0; jt < 7; ++jt) {
            int j = jt * 16 + l15;
            acc[jt][r] = (j < NTOK)
                ? (acc[jt][r] + mrow[i * NTOK + j] + brow[i * NTOK + j])
                : -__builtin_inff();
        }
        float m = acc[0][r];
        #pragma unroll
        for (int jt = 1; jt < 7; ++jt) m = fmaxf(m, acc[jt][r]);
        m = fmaxf(m, __shfl_xor(m, 1, 16));
        m = fmaxf(m, __shfl_xor(m, 2, 16));
        m = fmaxf(m, __shfl_xor(m, 4, 16));
        m = fmaxf(m, __shfl_xor(m, 8, 16));
        float s = 0.f;
        #pragma unroll
        for (int jt = 0; jt < 7; ++jt) {
            float e = __expf(acc[jt][r] - m);
            acc[jt][r] = e; s += e;
        }
        s += __shfl_xor(s, 1, 16);
        s += __shfl_xor(s, 2, 16);
        s += __shfl_xor(s, 4, 16);
        s += __shfl_xor(s, 8, 16);
        if (l15 == 0) invS[iact] = 1.f / s;
    }

    #pragma unroll
    for (int jt = 0; jt < 7; ++jt) {
        #pragma unroll
        for (int r = 0; r < 4; ++r) {
            int row = it * 16 + l16 * 4 + r;
            int j = jt * 16 + l15;
            *(bf16*)(P + row * 256 + (((j >> 3) ^ (row & 7)) << 4) + ((j & 7) << 1))
                = (bf16)acc[jt][r];
        }
    }
    __syncthreads();

    f32x4 o0 = z4, o1 = z4;
    const int prow = it * 16 + l15;
    #pragma unroll
    for (int ks = 0; ks < 4; ++ks) {
        int kchunk = ks * 4 + l16;
        bf16x8 pf = *(const bf16x8*)(P + prow * 256 + ((kchunk ^ (prow & 7)) << 4));
        bf16x8 v0 = *(const bf16x8*)(Vt + l15 * 256 + ((kchunk ^ (l15 & 7)) << 4));
        bf16x8 v1 = *(const bf16x8*)(Vt + (16 + l15) * 256 + ((kchunk ^ (l15 & 7)) << 4));
        o0 = MFMA(v0, pf, o0);
        o1 = MFMA(v1, pf, o1);
    }

    {
        int row = it * 16 + l15;
        if (row < NTOK) {
            float inv = invS[row];
            bf16* dst = ao + (size_t)b * NTOK * CDIM + h * HDIM;
            bf16x4 s0, s1;
            #pragma unroll
            for (int r = 0; r < 4; ++r) {
                s0[r] = (bf16)(o0[r] * inv);
                s1[r] = (bf16)(o1[r] * inv);
            }
            *(bf16x4*)(dst + (size_t)row * CDIM + l16 * 4)      = s0;
            *(bf16x4*)(dst + (size_t)row * CDIM + 16 + l16 * 4) = s1;
        }
    }
}

// ---------------------------------------------------------------------------
// Proj GEMM v6: same MLP structure as qkv v6 (16 rows/wave, 4-wave blocks,
// quad-buffered B prefetch, f32x4 coalesced stores).
// ---------------------------------------------------------------------------
__global__ __launch_bounds__(256) void proj_gemm(
    const bf16* __restrict__ ao, const bf16* __restrict__ wb,
    const float* __restrict__ bvec, float* __restrict__ out)
{
    const int tid = threadIdx.x, lane = tid & 63, wv = tid >> 6;
    const int l15 = lane & 15, l16 = lane >> 4;
    const int row = blockIdx.x * 64 + wv * 16 + l15;

    bf16x8 af[6];
    {
        const bf16* ar = ao + (size_t)row * CDIM + l16 * 8;
        #pragma unroll
        for (int ks = 0; ks < 6; ++ks)
            af[ks] = *(const bf16x8*)(ar + ks * 32);
    }

    const int orow = row * CDIM;
    const bf16* wlane = wb + (size_t)l15 * CDIM + l16 * 8;

    const f32x4 z4 = {0.f, 0.f, 0.f, 0.f};
    f32x4 acc[4];
    bf16x8 bbuf[4][4];

    #pragma unroll
    for (int p = 0; p < 3; ++p) {
        #pragma unroll
        for (int ct = 0; ct < 4; ++ct)
            bbuf[p][ct] = *(const bf16x8*)(wlane + (size_t)(ct * 16) * CDIM + p * 32);
    }

    #pragma unroll
    for (int t = 0; t < 18; ++t) {
        const int nc = t / 6, ks = t % 6;
        if (ks == 0) {
            #pragma unroll
            for (int ct = 0; ct < 4; ++ct) acc[ct] = z4;
        }
        if (t < 15) {
            const int tn = t + 3, nn = tn / 6, kk = tn % 6;
            #pragma unroll
            for (int ct = 0; ct < 4; ++ct)
                bbuf[tn & 3][ct] =
                    *(const bf16x8*)(wlane + (size_t)(nn * 64 + ct * 16) * CDIM + kk * 32);
        }
        #pragma unroll
        for (int ct = 0; ct < 4; ++ct)
            acc[ct] = MFMA(bbuf[t & 3][ct], af[ks], acc[ct]);

        if (ks == 5) {
            #pragma unroll
            for (int ct = 0; ct < 4; ++ct) {
                const int g0 = nc * 64 + ct * 16;
                const float4 bvf = *(const float4*)(bvec + g0 + l16 * 4);
                f32x4 s;
                #pragma unroll
                for (int r = 0; r < 4; ++r)
                    s[r] = acc[ct][r] + ((const float*)&bvf)[r];
                *(f32x4*)(out + (size_t)orow + g0 + l16 * 4) = s;
            }
        }
    }
}

// ---------------------------------------------------------------------------
extern "C" void kernel_launch(void* const* d_in, const int* in_sizes, int n_in,
                              void* d_out, int out_size, void* d_ws, size_t ws_size,
                              hipStream_t stream)
{
    (void)in_sizes; (void)n_in; (void)out_size; (void)ws_size;
    const float* x      = (const float*)d_in[0];
    const float* mask   = (const float*)d_in[1];
    const float* qkv_w  = (const float*)d_in[2];
    const float* qkv_b  = (const float*)d_in[3];
    const float* proj_w = (const float*)d_in[4];
    const float* proj_b = (const float*)d_in[5];
    const float* rpb    = (const float*)d_in[6];
    const int*   rel    = (const int*)d_in[7];
    float* out = (float*)d_out;

    char* ws = (char*)d_ws;
    bf16* qb = (bf16*)ws;
    bf16* kb = qb + QKV_ELEMS;
    bf16* vb = kb + QKV_ELEMS;
    size_t off = 3 * QKV_ELEMS * sizeof(bf16);
    float* bias = (float*)(ws + off);
    off += ((size_t)NHEAD * NN * 4 + 255) / 256 * 256;
    bf16* ao = (bf16*)(ws + off);
    // overlapped weight buffers:
    bf16* qwb = ao;            // live only until qkv_gemm; attn rewrites ao after
    bf16* pwb = qb;            // written after attn (qb dead), read by proj

    build_bias<<<(NN + 255) / 256, 256, 0, stream>>>(rpb, rel, bias);
    wconv<<<(3 * CDIM * CDIM + 255) / 256, 256, 0, stream>>>(qkv_w, qwb, 3 * CDIM * CDIM);
    qkv_gemm<<<200704 / 64, 256, 0, stream>>>(x, qwb, qkv_b, qb, kb, vb);
    attn_fused<<<B_TOT * NHEAD, 448, 0, stream>>>(qb, kb, vb, mask, bias, ao);
    wconv<<<(CDIM * CDIM + 255) / 256, 256, 0, stream>>>(proj_w, pwb, CDIM * CDIM);
    proj_gemm<<<200704 / 64, 256, 0, stream>>>(ao, pwb, proj_b, out);
}

// Round 9
// 369.190 us; speedup vs baseline: 2.1736x; 1.8309x over previous
//
#include <hip/hip_runtime.h>
#include <hip/hip_bf16.h>

using bf16   = __bf16;
using bf16x4 = __attribute__((ext_vector_type(4))) __bf16;
using bf16x8 = __attribute__((ext_vector_type(8))) __bf16;
using f32x4  = __attribute__((ext_vector_type(4))) float;

#define B_TOT 2048
#define NTOK  98
#define CDIM  192
#define NHEAD 6
#define HDIM  32
#define NWIN  512
#define NN    (NTOK*NTOK)            /* 9604 */
#define QKV_ELEMS ((size_t)B_TOT*NHEAD*NTOK*HDIM)  /* 38535168 */
#define MROWS 200704
#define SCALE 0.17677669529663687f   /* 32^-0.5 */

#define MFMA(a,b,c) __builtin_amdgcn_mfma_f32_16x16x32_bf16((a),(b),(c),0,0,0)

// async global->LDS, 16B per lane; LDS dest is wave-uniform base (+lane*16 by HW)
#define GLD16(gp, lp) __builtin_amdgcn_global_load_lds(                        \
    (const __attribute__((address_space(1))) void*)(gp),                       \
    (__attribute__((address_space(3))) void*)(lp), 16, 0, 0)

// ---------------------------------------------------------------------------
// bias[h][i][j] = rpb_table[rel_pos_index[i*98+j]][h]
// ---------------------------------------------------------------------------
__global__ void build_bias(const float* __restrict__ table,
                           const int* __restrict__ rel,
                           float* __restrict__ bias) {
    int t = blockIdx.x * 256 + threadIdx.x;
    if (t < NN) {
        int idx = rel[t];
        #pragma unroll
        for (int h = 0; h < NHEAD; ++h)
            bias[h * NN + t] = table[idx * NHEAD + h];
    }
}

// ---------------------------------------------------------------------------
// f32 -> bf16 converter with T2 row-XOR swizzle baked into storage:
// dst[row][ (c ^ (row&7))*8 .. +8 ] = src[row][c*8 .. +8], c = 16B chunk 0..23.
// Swizzle key = GLOBAL flat row index (consumers read with (m0+arow)&7).
// ---------------------------------------------------------------------------
__global__ void conv_swz(const float* __restrict__ src, bf16* __restrict__ dst,
                         int nchunk) {
    int t = blockIdx.x * 256 + threadIdx.x;
    if (t < nchunk) {
        int row = t / 24, c = t % 24;
        const float* s = src + (size_t)row * CDIM + c * 8;
        bf16x8 o;
        #pragma unroll
        for (int e = 0; e < 8; ++e) o[e] = (bf16)s[e];
        *(bf16x8*)(dst + (size_t)row * CDIM + ((c ^ (row & 7)) << 3)) = o;
    }
}

// ---------------------------------------------------------------------------
// QKV GEMM v7 (m97-style 2-phase): BM=64, 256 thr (4 waves x 16 rows).
// A-tile (24KB) via global_load_lds once, A-frags hoisted to regs;
// B double-buffered in LDS (2x24KB), async-staged one chunk ahead,
// ONE barrier per chunk. All LDS reads conflict-free via baked swizzle.
// ---------------------------------------------------------------------------
__global__ __launch_bounds__(256) void qkv_gemm(
    const bf16* __restrict__ xb, const bf16* __restrict__ wb,
    const float* __restrict__ bvec,
    bf16* __restrict__ qdst, bf16* __restrict__ kdst, bf16* __restrict__ vdst)
{
    __shared__ char As[24576];
    __shared__ char Bs[2][24576];
    const int tid = threadIdx.x, lane = tid & 63, wv = tid >> 6;
    const int l15 = lane & 15, l16 = lane >> 4;
    const int m0 = blockIdx.x * 64;

    // stage A tile + B chunk 0 (each wave moves 6 x 1KB of each)
    {
        const char* asrc = (const char*)xb + (size_t)m0 * 384;
        const char* bsrc = (const char*)wb;
        #pragma unroll
        for (int j = 0; j < 6; ++j) {
            const int ch = wv * 6 + j;
            GLD16(asrc + ch * 1024 + lane * 16, As + ch * 1024);
            GLD16(bsrc + ch * 1024 + lane * 16, Bs[0] + ch * 1024);
        }
    }
    __syncthreads();   // drains vmcnt: A + B0 resident

    // hoist A fragments (wave owns rows wv*16 .. +16)
    const int arow = wv * 16 + l15;
    bf16x8 af[6];
    #pragma unroll
    for (int ks = 0; ks < 6; ++ks)
        af[ks] = *(const bf16x8*)(As + arow * 384 + (((ks * 4 + l16) ^ (arow & 7)) << 4));

    const int grow   = m0 + arow;
    const int rowoff = (grow / NTOK) * 18816 + (grow % NTOK) * 32;

    const f32x4 z4 = {0.f, 0.f, 0.f, 0.f};

    #pragma unroll
    for (int nc = 0; nc < 9; ++nc) {
        if (nc < 8) {   // async-stage next B chunk before compute (T3 recipe)
            const char* bsrc = (const char*)wb + (size_t)(nc + 1) * 24576;
            #pragma unroll
            for (int j = 0; j < 6; ++j) {
                const int ch = wv * 6 + j;
                GLD16(bsrc + ch * 1024 + lane * 16, Bs[(nc + 1) & 1] + ch * 1024);
            }
        }

        f32x4 acc[4];
        #pragma unroll
        for (int ct = 0; ct < 4; ++ct) acc[ct] = z4;

        #pragma unroll
        for (int ks = 0; ks < 6; ++ks) {
            #pragma unroll
            for (int ct = 0; ct < 4; ++ct) {
                const int brow = ct * 16 + l15;
                bf16x8 bf = *(const bf16x8*)(Bs[nc & 1] + brow * 384
                                             + (((ks * 4 + l16) ^ (brow & 7)) << 4));
                acc[ct] = MFMA(bf, af[ks], acc[ct]);
            }
        }

        // epilogue for chunk nc: lane holds row = grow, cols g0 + l16*4 + r
        #pragma unroll
        for (int ct = 0; ct < 4; ++ct) {
            const int g0    = nc * 64 + ct * 16;   // compile-time
            const int which = g0 / CDIM;
            const int cm    = g0 % CDIM;
            const int h     = cm >> 5, hd0 = cm & 31;
            const float4 bvf = *(const float4*)(bvec + g0 + l16 * 4);
            bf16x4 s;
            #pragma unroll
            for (int r = 0; r < 4; ++r) {
                float v = acc[ct][r] + ((const float*)&bvf)[r];
                if (which == 0) v *= SCALE;
                s[r] = (bf16)v;
            }
            bf16* dp = (which == 0) ? qdst : (which == 1) ? kdst : vdst;
            *(bf16x4*)(dp + rowoff + h * 3136 + hd0 + l16 * 4) = s;
        }
        __syncthreads();   // B(nc+1) resident; reads of Bs[nc&1] complete
    }
}

// ---------------------------------------------------------------------------
// Fused attention (r5 structure): one block per (window, head), 7 waves, one
// barrier, deferred softmax norm, XCD-chunked swizzle. ao stored with the
// row-XOR chunk swizzle KEYED ON THE GLOBAL FLAT ROW (b*98+row) so proj_gemm
// can stage it via global_load_lds (this was the round-8 bug: used row&7).
// ---------------------------------------------------------------------------
__global__ __launch_bounds__(448) void attn_fused(
    const bf16* __restrict__ q, const bf16* __restrict__ k,
    const bf16* __restrict__ v,
    const float* __restrict__ mask, const float* __restrict__ bias,
    bf16* __restrict__ ao)
{
    __shared__ char lds[8192 + 28672 + 512];
    char* Vt = lds;           // 32 x 128 bf16, 256B rows, swizzled
    char* P  = lds + 8192;    // 112 x 128 bf16, 256B rows, swizzled
    float* invS = (float*)(lds + 8192 + 28672);   // 112 floats

    const int bid = blockIdx.x;
    const int bh  = (bid & 7) * 1536 + (bid >> 3);
    const int b = bh / NHEAD, h = bh % NHEAD;
    const int w = b & (NWIN - 1);
    const int tid = threadIdx.x, lane = tid & 63, it = tid >> 6;
    const int l15 = lane & 15, l16 = lane >> 4;

    const size_t bho = (size_t)bh * 3136;
    if (tid < 392) {
        int n = tid >> 2, hd0 = (tid & 3) * 8;
        bf16x8 vv = *(const bf16x8*)(v + bho + n * 32 + hd0);
        #pragma unroll
        for (int e = 0; e < 8; ++e) {
            int hd = hd0 + e;
            *(bf16*)(Vt + hd * 256 + (((n >> 3) ^ (hd & 7)) << 4) + ((n & 7) << 1)) = vv[e];
        }
    }
    for (int f = tid; f < 32 * 30; f += 448) {
        int hd = f / 30, n = 98 + f % 30;
        *(bf16*)(Vt + hd * 256 + (((n >> 3) ^ (hd & 7)) << 4) + ((n & 7) << 1)) = (bf16)0.f;
    }
    {
        int zr = it * 16 + l15;
        int zc = 112 + l16 * 4;
        *(unsigned long long*)(P + zr * 256 + (((zc >> 3) ^ (zr & 7)) << 4) + ((zc & 7) << 1)) = 0ull;
    }

    int qrow = it * 16 + l15; if (qrow > 97) qrow = 97;
    const bf16* qsrc = q + bho;
    const bf16* ksrc = k + bho;
    const bf16x8 qf = *(const bf16x8*)(qsrc + qrow * HDIM + l16 * 8);
    const f32x4 z4 = {0.f, 0.f, 0.f, 0.f};
    f32x4 acc[7];
    #pragma unroll
    for (int jt = 0; jt < 7; ++jt) {
        int kr = jt * 16 + l15; if (kr > 97) kr = 97;
        bf16x8 kf = *(const bf16x8*)(ksrc + kr * HDIM + l16 * 8);
        acc[jt] = MFMA(qf, kf, z4);
    }

    const float* mrow = mask + (size_t)w * NN;
    const float* brow = bias + (size_t)h * NN;
    #pragma unroll
    for (int r = 0; r < 4; ++r) {
        const int iact = it * 16 + l16 * 4 + r;
        int i = iact > 97 ? 97 : iact;
        #pragma unroll
        for (int jt = 0; jt < 7; ++jt) {
            int j = jt * 16 + l15;
            acc[jt][r] = (j < NTOK)
                ? (acc[jt][r] + mrow[i * NTOK + j] + brow[i * NTOK + j])
                : -__builtin_inff();
        }
        float m = acc[0][r];
        #pragma unroll
        for (int jt = 1; jt < 7; ++jt) m = fmaxf(m, acc[jt][r]);
        m = fmaxf(m, __shfl_xor(m, 1, 16));
        m = fmaxf(m, __shfl_xor(m, 2, 16));
        m = fmaxf(m, __shfl_xor(m, 4, 16));
        m = fmaxf(m, __shfl_xor(m, 8, 16));
        float s = 0.f;
        #pragma unroll
        for (int jt = 0; jt < 7; ++jt) {
            float e = __expf(acc[jt][r] - m);
            acc[jt][r] = e; s += e;
        }
        s += __shfl_xor(s, 1, 16);
        s += __shfl_xor(s, 2, 16);
        s += __shfl_xor(s, 4, 16);
        s += __shfl_xor(s, 8, 16);
        if (l15 == 0) invS[iact] = 1.f / s;
    }

    #pragma unroll
    for (int jt = 0; jt < 7; ++jt) {
        #pragma unroll
        for (int r = 0; r < 4; ++r) {
            int row = it * 16 + l16 * 4 + r;
            int j = jt * 16 + l15;
            *(bf16*)(P + row * 256 + (((j >> 3) ^ (row & 7)) << 4) + ((j & 7) << 1))
                = (bf16)acc[jt][r];
        }
    }
    __syncthreads();

    f32x4 o0 = z4, o1 = z4;
    const int prow = it * 16 + l15;
    #pragma unroll
    for (int ks = 0; ks < 4; ++ks) {
        int kchunk = ks * 4 + l16;
        bf16x8 pf = *(const bf16x8*)(P + prow * 256 + ((kchunk ^ (prow & 7)) << 4));
        bf16x8 v0 = *(const bf16x8*)(Vt + l15 * 256 + ((kchunk ^ (l15 & 7)) << 4));
        bf16x8 v1 = *(const bf16x8*)(Vt + (16 + l15) * 256 + ((kchunk ^ (l15 & 7)) << 4));
        o0 = MFMA(v0, pf, o0);
        o1 = MFMA(v1, pf, o1);
    }

    {
        int row = it * 16 + l15;
        if (row < NTOK) {
            float inv = invS[row];
            bf16* dst = ao + (size_t)b * NTOK * CDIM;
            bf16x4 s0, s1;
            #pragma unroll
            for (int r = 0; r < 4; ++r) {
                s0[r] = (bf16)(o0[r] * inv);
                s1[r] = (bf16)(o1[r] * inv);
            }
            // swizzled store keyed on GLOBAL flat row (b*98+row):
            const int swr = (b * NTOK + row) & 7;       // == (2*b + row) & 7
            const int c0 = h * 4 + (l16 >> 1);          // e0 = h*32 + l16*4
            const int c1 = c0 + 2;                      // e1 = e0 + 16
            const int wi = (l16 & 1) << 2;              // within-chunk elem off
            *(bf16x4*)(dst + (size_t)row * CDIM + (((c0 ^ swr) << 3) | wi)) = s0;
            *(bf16x4*)(dst + (size_t)row * CDIM + (((c1 ^ swr) << 3) | wi)) = s1;
        }
    }
}

// ---------------------------------------------------------------------------
// Proj GEMM v7: same 2-phase structure as qkv v7. A = swizzled ao via
// global_load_lds; B = swizzled pwb, 3 chunks, double-buffered. f32 out.
// ---------------------------------------------------------------------------
__global__ __launch_bounds__(256) void proj_gemm(
    const bf16* __restrict__ ao, const bf16* __restrict__ wb,
    const float* __restrict__ bvec, float* __restrict__ out)
{
    __shared__ char As[24576];
    __shared__ char Bs[2][24576];
    const int tid = threadIdx.x, lane = tid & 63, wv = tid >> 6;
    const int l15 = lane & 15, l16 = lane >> 4;
    const int m0 = blockIdx.x * 64;

    {
        const char* asrc = (const char*)ao + (size_t)m0 * 384;
        const char* bsrc = (const char*)wb;
        #pragma unroll
        for (int j = 0; j < 6; ++j) {
            const int ch = wv * 6 + j;
            GLD16(asrc + ch * 1024 + lane * 16, As + ch * 1024);
            GLD16(bsrc + ch * 1024 + lane * 16, Bs[0] + ch * 1024);
        }
    }
    __syncthreads();

    const int arow = wv * 16 + l15;
    bf16x8 af[6];
    #pragma unroll
    for (int ks = 0; ks < 6; ++ks)
        af[ks] = *(const bf16x8*)(As + arow * 384 + (((ks * 4 + l16) ^ (arow & 7)) << 4));

    const size_t orow = (size_t)(m0 + arow) * CDIM;
    const f32x4 z4 = {0.f, 0.f, 0.f, 0.f};

    #pragma unroll
    for (int nc = 0; nc < 3; ++nc) {
        if (nc < 2) {
            const char* bsrc = (const char*)wb + (size_t)(nc + 1) * 24576;
            #pragma unroll
            for (int j = 0; j < 6; ++j) {
                const int ch = wv * 6 + j;
                GLD16(bsrc + ch * 1024 + lane * 16, Bs[(nc + 1) & 1] + ch * 1024);
            }
        }

        f32x4 acc[4];
        #pragma unroll
        for (int ct = 0; ct < 4; ++ct) acc[ct] = z4;

        #pragma unroll
        for (int ks = 0; ks < 6; ++ks) {
            #pragma unroll
            for (int ct = 0; ct < 4; ++ct) {
                const int brow = ct * 16 + l15;
                bf16x8 bf = *(const bf16x8*)(Bs[nc & 1] + brow * 384
                                             + (((ks * 4 + l16) ^ (brow & 7)) << 4));
                acc[ct] = MFMA(bf, af[ks], acc[ct]);
            }
        }

        #pragma unroll
        for (int ct = 0; ct < 4; ++ct) {
            const int g0 = nc * 64 + ct * 16;
            const float4 bvf = *(const float4*)(bvec + g0 + l16 * 4);
            f32x4 s;
            #pragma unroll
            for (int r = 0; r < 4; ++r)
                s[r] = acc[ct][r] + ((const float*)&bvf)[r];
            *(f32x4*)(out + orow + g0 + l16 * 4) = s;
        }
        __syncthreads();
    }
}

// ---------------------------------------------------------------------------
extern "C" void kernel_launch(void* const* d_in, const int* in_sizes, int n_in,
                              void* d_out, int out_size, void* d_ws, size_t ws_size,
                              hipStream_t stream)
{
    (void)in_sizes; (void)n_in; (void)out_size; (void)ws_size;
    const float* x      = (const float*)d_in[0];
    const float* mask   = (const float*)d_in[1];
    const float* qkv_w  = (const float*)d_in[2];
    const float* qkv_b  = (const float*)d_in[3];
    const float* proj_w = (const float*)d_in[4];
    const float* proj_b = (const float*)d_in[5];
    const float* rpb    = (const float*)d_in[6];
    const int*   rel    = (const int*)d_in[7];
    float* out = (float*)d_out;

    char* ws = (char*)d_ws;
    bf16* qb = (bf16*)ws;
    bf16* kb = qb + QKV_ELEMS;
    bf16* vb = kb + QKV_ELEMS;
    size_t off = 3 * QKV_ELEMS * sizeof(bf16);
    float* bias = (float*)(ws + off);
    off += ((size_t)NHEAD * NN * 4 + 255) / 256 * 256;
    bf16* ao = (bf16*)(ws + off);
    // overlapped buffers (same ws footprint as before):
    bf16* qwb = ao;               // swizzled qkv_w; dead before attn writes ao
    bf16* pwb = qb;               // swizzled proj_w; written after attn (qb dead)
    bf16* xb  = (bf16*)d_out;     // swizzled bf16 x; dead before proj writes out

    build_bias<<<(NN + 255) / 256, 256, 0, stream>>>(rpb, rel, bias);
    conv_swz<<<(MROWS * 24 + 255) / 256, 256, 0, stream>>>(x, xb, MROWS * 24);
    conv_swz<<<(576 * 24 + 255) / 256, 256, 0, stream>>>(qkv_w, qwb, 576 * 24);
    qkv_gemm<<<MROWS / 64, 256, 0, stream>>>(xb, qwb, qkv_b, qb, kb, vb);
    attn_fused<<<B_TOT * NHEAD, 448, 0, stream>>>(qb, kb, vb, mask, bias, ao);
    conv_swz<<<(192 * 24 + 255) / 256, 256, 0, stream>>>(proj_w, pwb, 192 * 24);
    proj_gemm<<<MROWS / 64, 256, 0, stream>>>(ao, pwb, proj_b, out);
}